// Round 3
// baseline (316.795 us; speedup 1.0000x reference)
//
#include <hip/hip_runtime.h>
#include <hip/hip_bf16.h>
#include <stdint.h>

#define BATCH 8
#define SEQ   4096
#define EMB   1024
#define HD    128
#define NROWS 32768

typedef __attribute__((ext_vector_type(8))) short short8;
typedef __attribute__((ext_vector_type(4))) float f32x4;

__device__ inline unsigned short f2bf(float f) {
    union { float f; unsigned int u; } c; c.f = f;
    unsigned int u = c.u;
    unsigned int r = (u + 0x7fffu + ((u >> 16) & 1u)) >> 16;
    return (unsigned short)r;
}
__device__ inline float bf2f(unsigned short u) {
    union { unsigned int i; float f; } c; c.i = ((unsigned int)u) << 16; return c.f;
}
__device__ inline unsigned int pkbf(float a, float b) {
    __hip_bfloat162 h = __float22bfloat162_rn(make_float2(a, b));
    union { __hip_bfloat162 h; unsigned int u; } c; c.h = h; return c.u;
}

#define GLDS16(gp, lp) __builtin_amdgcn_global_load_lds( \
    (const __attribute__((address_space(1))) void*)(gp), \
    (__attribute__((address_space(3))) void*)(lp), 16, 0, 0)

// ---- stream-K work decomposition helpers (all block-uniform scalar) -------
// items per batch = sum_qt 2(qt+1) = 1056; total = 8448.
// chunks: blocks 0..255 own 17 items, 256..511 own 16 (256*17+256*16 = 8448).
__device__ inline void decomp(int it, int& b, int& qt, int& kv) {
    b = it / 1056;
    int r = it - b * 1056;
    int q = (int)((__builtin_sqrtf(4.0f * (float)r + 1.0f) - 1.0f) * 0.5f);
    while ((q + 1) * (q + 2) <= r) ++q;
    while (q * (q + 1) > r) --q;
    qt = q;
    kv = r - q * (q + 1);
}
__device__ inline int chunk_of(int I) {
    return (I < 4352) ? (I / 17) : (256 + ((I - 4352) >> 4));
}
// j>=1 overflow-slot base per batch (widths 1/2/3/4 by qt band; 80/batch)
__device__ inline int base1(int qt) {
    if (qt < 8)  return qt;
    if (qt < 16) return 8 + 2 * (qt - 8);
    if (qt < 24) return 24 + 3 * (qt - 16);
    return 48 + 4 * (qt - 24);
}

// ---------------------------------------------------------------------------
// prep: wt[n][k] = bf16(W[k][h]) for n = sel*128+h. 384 blocks, one row each.
// ---------------------------------------------------------------------------
__global__ __launch_bounds__(256) void prep_kernel(
    const float* __restrict__ Wq, const float* __restrict__ bq,
    const float* __restrict__ Wk, const float* __restrict__ bk,
    const float* __restrict__ Wv, const float* __restrict__ bv,
    unsigned short* __restrict__ wt, float* __restrict__ biasc)
{
    const int n = blockIdx.x;           // 0..383
    const int sel = n >> 7, h = n & 127;
    const float* W = (sel == 0) ? Wq : (sel == 1) ? Wk : Wv;
    const int tid = threadIdx.x;
    const int k0 = tid * 4;
    union { unsigned short us[4]; uint2 v; } pk;
#pragma unroll
    for (int u = 0; u < 4; ++u) pk.us[u] = f2bf(W[(size_t)(k0 + u) * HD + h]);
    *(uint2*)&wt[(size_t)n * EMB + k0] = pk.v;
    if (tid == 0) {
        const float* bp = (sel == 0) ? bq : (sel == 1) ? bk : bv;
        biasc[n] = bp[h];
    }
}

// ---------------------------------------------------------------------------
// gemm_qkv v2: fused QKV. 256 blocks x 128 rows x all 384 cols; 12 waves
// (768 thr), wave tile 64 rows x 64 cols, acc[4][4].
// ---------------------------------------------------------------------------
__global__ __launch_bounds__(768, 3) void gemm_qkv(
    const float* __restrict__ x, const unsigned short* __restrict__ wt,
    const float* __restrict__ biasc,
    unsigned short* __restrict__ q, unsigned short* __restrict__ kOut,
    unsigned short* __restrict__ vt)
{
    const int m0  = blockIdx.x * 128;
    const int tid = threadIdx.x;
    const int wave = tid >> 6, lane = tid & 63;
    const int quad = lane >> 4, l15 = lane & 15;
    const int wm = (wave >= 6) ? 1 : 0;      // 2 M-waves x 6 N-waves
    const int wn = wave - wm * 6;            // 0..5, 64 cols each

    __shared__ __align__(16) unsigned short As[2][128][40];   // +8 pad
    __shared__ __align__(16) unsigned short Bs[2][12288];     // [384][32] swizzled

    f32x4 acc[4][4];
#pragma unroll
    for (int i = 0; i < 4; ++i)
#pragma unroll
        for (int j = 0; j < 4; ++j) acc[i][j] = (f32x4){0.f, 0.f, 0.f, 0.f};

    const int aactive = (tid < 512);
    const int arow = tid >> 3, akc = (tid & 7) * 4;
    float4 aR0, aR1;

#define LOAD_A(kt)                                                          \
    if (aactive) {                                                          \
        aR0 = *(const float4*)(x + (size_t)(m0 + arow) * EMB + (kt) * 32 + akc);        \
        aR1 = *(const float4*)(x + (size_t)(m0 + arow + 64) * EMB + (kt) * 32 + akc);   \
    }
#define WRITE_A(buf)                                                        \
    if (aactive) {                                                          \
        union { unsigned short us[4]; uint2 v; } p0, p1;                    \
        p0.us[0] = f2bf(aR0.x); p0.us[1] = f2bf(aR0.y);                     \
        p0.us[2] = f2bf(aR0.z); p0.us[3] = f2bf(aR0.w);                     \
        *(uint2*)&As[buf][arow][akc] = p0.v;                                \
        p1.us[0] = f2bf(aR1.x); p1.us[1] = f2bf(aR1.y);                     \
        p1.us[2] = f2bf(aR1.z); p1.us[3] = f2bf(aR1.w);                     \
        *(uint2*)&As[buf][arow + 64][akc] = p1.v;                           \
    }
#define STAGE_B(kt, buf)                                                    \
    {                                                                       \
        _Pragma("unroll")                                                   \
        for (int g = 0; g < 2; ++g) {                                       \
            int s0 = (g * 12 + wave) * 64;                                  \
            int s  = s0 + lane;                                             \
            int n  = s >> 2, c = (s & 3) ^ (n & 3);                         \
            GLDS16(wt + (size_t)n * EMB + (kt) * 32 + c * 8,                \
                   &Bs[buf][s0 * 8]);                                       \
        }                                                                   \
    }

    LOAD_A(0); STAGE_B(0, 0); WRITE_A(0);
    int cur = 0;

    for (int kt = 0; kt < 32; ++kt) {
        __syncthreads();
        if (kt < 31) { LOAD_A(kt + 1); STAGE_B(kt + 1, cur ^ 1); }
        short8 af[4], bw[4];
#pragma unroll
        for (int mj = 0; mj < 4; ++mj)
            af[mj] = *(const short8*)&As[cur][wm * 64 + mj * 16 + l15][quad * 8];
#pragma unroll
        for (int ni = 0; ni < 4; ++ni) {
            int n = wn * 64 + ni * 16 + l15;
            bw[ni] = *(const short8*)&Bs[cur][n * 32 + ((quad ^ (n & 3)) << 3)];
        }
#pragma unroll
        for (int ni = 0; ni < 4; ++ni)
#pragma unroll
            for (int mj = 0; mj < 4; ++mj)
                acc[ni][mj] = __builtin_amdgcn_mfma_f32_16x16x32_bf16(
                    bw[ni], af[mj], acc[ni][mj], 0, 0, 0);
        if (kt < 31) WRITE_A(cur ^ 1);
        cur ^= 1;
    }

    const float qscale = 0.08838834764831845f * 1.4426950408889634f;
    const int bb = m0 >> 12;
    const int t0 = m0 & 4095;
    const int mrow0 = m0 + wm * 64;
    const int tl0   = t0 + wm * 64;
#pragma unroll
    for (int ni = 0; ni < 4; ++ni) {
        int colbase = wn * 64 + ni * 16;
        int sel = colbase >> 7;
        int c0 = colbase + quad * 4;
        float4 bv4 = *(const float4*)&biasc[c0];
#pragma unroll
        for (int mj = 0; mj < 4; ++mj) {
            int m = mrow0 + mj * 16 + l15;
            if (sel == 0) {
                union { unsigned short us[4]; uint2 v; } pk;
#pragma unroll
                for (int j = 0; j < 4; ++j)
                    pk.us[j] = f2bf((acc[ni][mj][j] + ((const float*)&bv4)[j]) * qscale);
                *(uint2*)&q[(size_t)m * HD + (c0 & 127)] = pk.v;
            } else if (sel == 1) {
                union { unsigned short us[4]; uint2 v; } pk;
#pragma unroll
                for (int j = 0; j < 4; ++j)
                    pk.us[j] = f2bf(acc[ni][mj][j] + ((const float*)&bv4)[j]);
                *(uint2*)&kOut[(size_t)m * HD + (c0 & 127)] = pk.v;
            } else {
#pragma unroll
                for (int j = 0; j < 4; ++j) {
                    int h = (c0 & 127) + j;
                    vt[((size_t)(bb * 128 + h)) * SEQ + tl0 + mj * 16 + l15] =
                        f2bf(acc[ni][mj][j] + ((const float*)&bv4)[j]);
                }
            }
        }
    }
#undef LOAD_A
#undef WRITE_A
#undef STAGE_B
}

// ---------------------------------------------------------------------------
// attn v3: stream-K flash attention. 512 blocks x 256 thr (4 waves), every
// block processes EXACTLY 16/17 KV-tile items from the flattened (b,qt,kv)
// work list -> all blocks equal-length, occupancy stays 8 waves/CU for the
// whole kernel (fixes the v2 failure: co-resident blocks overlap, so wall
// followed max(niter)=32, not the per-CU sum). Context switches flush
// unnormalized fp32 (O,m,l) segments: seg j=0 in-place into out, j>=1 into
// Oseg slots (closed-form <=80/batch). merge_kernel combines 1..5 segs.
// Per-item compute body identical to v2; + s_setprio(1) around MFMA.
// ---------------------------------------------------------------------------
__global__ __launch_bounds__(256, 2) void attn_kernel(
    const unsigned short* __restrict__ q, const unsigned short* __restrict__ k,
    const unsigned short* __restrict__ vt, float* __restrict__ out,
    float* __restrict__ Oseg, float2* __restrict__ ml)
{
    const int rank  = blockIdx.x;             // 0..511
    const int start = (rank < 256) ? 17 * rank : 4352 + ((rank - 256) << 4);
    const int iend  = start + ((rank < 256) ? 17 : 16);

    const int tid  = threadIdx.x;
    const int wave = tid >> 6, lane = tid & 63;
    const int quad = lane >> 4, l15 = lane & 15;

    __shared__ __align__(16) unsigned short Ks[2][8192];  // [64 key][16 ch sw]
    __shared__ __align__(16) unsigned short Vs[2][8192];  // [128 h][8 ch sw]

    const int bpa0 = (l15 + 16 * ((2 * quad) & 3)) * 4;   // bpermute byte addrs
    const int bpa1 = (l15 + 16 * ((2 * quad + 1) & 3)) * 4;

#define STAGE_KV(b_, kv_, buf_)                                              \
    {                                                                        \
        const size_t kb0 = (size_t)(b_) * SEQ + (kv_) * 64;                  \
        const size_t vb0 = (size_t)(b_) * HD * SEQ + (kv_) * 64;             \
        _Pragma("unroll")                                                    \
        for (int g = 0; g < 4; ++g) {                                        \
            int s0 = (g * 4 + wave) * 64;                                    \
            int s  = s0 + lane;                                              \
            int key = s >> 4, c = (s & 15) ^ (key & 15);                     \
            GLDS16(k + (kb0 + key) * HD + c * 8, &Ks[buf_][s0 * 8]);         \
        }                                                                    \
        _Pragma("unroll")                                                    \
        for (int g = 0; g < 4; ++g) {                                        \
            int s0 = (g * 4 + wave) * 64;                                    \
            int s  = s0 + lane;                                              \
            int h = s >> 3, c = (s & 7) ^ (h & 7);                           \
            GLDS16(vt + vb0 + (size_t)h * SEQ + c * 8, &Vs[buf_][s0 * 8]);   \
        }                                                                    \
    }

    int b, qt, kv;
    decomp(start, b, qt, kv);

    short8 qf[2][4];
    f32x4  o[2][8];
    float  m_r[2], l_r[2];
    int    qrow0 = 0;

#define CTX_INIT(b_, q_)                                                     \
    {                                                                        \
        qrow0 = (q_) * 128 + wave * 32;                                      \
        const size_t qoff = (size_t)(b_) * SEQ + qrow0;                      \
        _Pragma("unroll")                                                    \
        for (int mi = 0; mi < 2; ++mi)                                       \
            _Pragma("unroll")                                                \
            for (int kh = 0; kh < 4; ++kh)                                   \
                qf[mi][kh] = *(const short8*)(q + (qoff + mi * 16 + l15) * HD + kh * 32 + quad * 8); \
        _Pragma("unroll")                                                    \
        for (int mi = 0; mi < 2; ++mi) {                                     \
            _Pragma("unroll")                                                \
            for (int hi = 0; hi < 8; ++hi) o[mi][hi] = (f32x4){0.f, 0.f, 0.f, 0.f}; \
            m_r[mi] = -1e30f; l_r[mi] = 0.f;                                 \
        }                                                                    \
    }

#define CTX_FLUSH()                                                          \
    {                                                                        \
        const int I0 = b * 1056 + qt * (qt + 1);                             \
        const int j  = rank - chunk_of(I0);                                  \
        const int rr = wave * 32;                                            \
        float* obase;                                                        \
        if (j == 0) obase = out + ((size_t)b * SEQ + qrow0) * HD;            \
        else obase = Oseg + ((size_t)(b * 80 + base1(qt) + j - 1) * 128 + rr) * HD; \
        const size_t mlb = ((size_t)(b * 32 + qt) * 5 + j) * 128 + rr;       \
        _Pragma("unroll")                                                    \
        for (int mi = 0; mi < 2; ++mi) {                                     \
            if (quad == 0) ml[mlb + mi * 16 + l15] = make_float2(m_r[mi], l_r[mi]); \
            _Pragma("unroll")                                                \
            for (int hi = 0; hi < 8; ++hi)                                   \
                *(f32x4*)&obase[(size_t)(mi * 16 + l15) * HD + hi * 16 + quad * 4] = o[mi][hi]; \
        }                                                                    \
    }

    STAGE_KV(b, kv, 0);
    CTX_INIT(b, qt);
    int cur = 0;

    for (int it = start; it < iend; ++it) {
        int b2 = 0, qt2 = 0, kv2 = 0;
        const bool more = (it + 1 < iend);
        if (more) decomp(it + 1, b2, qt2, kv2);

        __syncthreads();                     // buf[cur] staged; prev reads retired
        if (more) STAGE_KV(b2, kv2, cur ^ 1);

        const int key0 = kv * 64;
        // ---- S^T = K Q^T : D[key][qrow], lane=qrow, regs=keys ----
        f32x4 s[2][4];
#pragma unroll
        for (int mi = 0; mi < 2; ++mi)
#pragma unroll
            for (int ni = 0; ni < 4; ++ni) s[mi][ni] = (f32x4){0.f, 0.f, 0.f, 0.f};
        __builtin_amdgcn_s_setprio(1);
#pragma unroll
        for (int kh = 0; kh < 4; ++kh) {
#pragma unroll
            for (int ni = 0; ni < 4; ++ni) {
                short8 kf = *(const short8*)&Ks[cur][(ni * 16 + l15) * 128 + (((kh * 4 + quad) ^ l15) << 3)];
                s[0][ni] = __builtin_amdgcn_mfma_f32_16x16x32_bf16(kf, qf[0][kh], s[0][ni], 0, 0, 0);
                s[1][ni] = __builtin_amdgcn_mfma_f32_16x16x32_bf16(kf, qf[1][kh], s[1][ni], 0, 0, 0);
            }
        }
        __builtin_amdgcn_s_setprio(0);
        // ---- causal mask (only diagonal tiles) ----
        if (key0 + 63 > qrow0) {
#pragma unroll
            for (int mi = 0; mi < 2; ++mi)
#pragma unroll
                for (int ni = 0; ni < 4; ++ni)
#pragma unroll
                    for (int j = 0; j < 4; ++j) {
                        int key = key0 + ni * 16 + quad * 4 + j;
                        int t   = qrow0 + mi * 16 + l15;
                        if (key > t) s[mi][ni][j] = -1e30f;
                    }
        }
        // ---- online softmax (scalar per lane) + P pack, defer-max ----
        unsigned int pk[2][4][2];
#pragma unroll
        for (int mi = 0; mi < 2; ++mi) {
            float mx = -1e30f;
#pragma unroll
            for (int ni = 0; ni < 4; ++ni)
#pragma unroll
                for (int j = 0; j < 4; ++j) mx = fmaxf(mx, s[mi][ni][j]);
            mx = fmaxf(mx, __shfl_xor(mx, 16));
            mx = fmaxf(mx, __shfl_xor(mx, 32));
            if (!__all(mx - m_r[mi] <= 8.0f)) {
                float mnew = fmaxf(m_r[mi], mx);
                float alpha = __builtin_amdgcn_exp2f(m_r[mi] - mnew);
                m_r[mi] = mnew;
                l_r[mi] *= alpha;
#pragma unroll
                for (int hi = 0; hi < 8; ++hi) o[mi][hi] *= alpha;
            }
            const float mcur = m_r[mi];
            float rs = 0.f;
#pragma unroll
            for (int ni = 0; ni < 4; ++ni) {
                float p0 = __builtin_amdgcn_exp2f(s[mi][ni][0] - mcur);
                float p1 = __builtin_amdgcn_exp2f(s[mi][ni][1] - mcur);
                float p2 = __builtin_amdgcn_exp2f(s[mi][ni][2] - mcur);
                float p3 = __builtin_amdgcn_exp2f(s[mi][ni][3] - mcur);
                rs += (p0 + p1) + (p2 + p3);
                pk[mi][ni][0] = pkbf(p0, p1);
                pk[mi][ni][1] = pkbf(p2, p3);
            }
            rs += __shfl_xor(rs, 16);
            rs += __shfl_xor(rs, 32);
            l_r[mi] += rs;
        }
        // ---- P^T B-frags via cross-quad bpermute ----
        short8 pT[2][2];
#pragma unroll
        for (int mi = 0; mi < 2; ++mi)
#pragma unroll
            for (int sk = 0; sk < 2; ++sk) {
                union { unsigned int u[4]; short8 s8; } pt;
                int lo = 2 * sk, hi_ = 2 * sk + 1;
                unsigned int a0 = (unsigned)__builtin_amdgcn_ds_bpermute(bpa0, (int)pk[mi][lo][0]);
                unsigned int b0 = (unsigned)__builtin_amdgcn_ds_bpermute(bpa0, (int)pk[mi][hi_][0]);
                pt.u[0] = (quad < 2) ? a0 : b0;
                unsigned int a1 = (unsigned)__builtin_amdgcn_ds_bpermute(bpa0, (int)pk[mi][lo][1]);
                unsigned int b1 = (unsigned)__builtin_amdgcn_ds_bpermute(bpa0, (int)pk[mi][hi_][1]);
                pt.u[1] = (quad < 2) ? a1 : b1;
                unsigned int a2 = (unsigned)__builtin_amdgcn_ds_bpermute(bpa1, (int)pk[mi][lo][0]);
                unsigned int b2 = (unsigned)__builtin_amdgcn_ds_bpermute(bpa1, (int)pk[mi][hi_][0]);
                pt.u[2] = (quad < 2) ? a2 : b2;
                unsigned int a3 = (unsigned)__builtin_amdgcn_ds_bpermute(bpa1, (int)pk[mi][lo][1]);
                unsigned int b3 = (unsigned)__builtin_amdgcn_ds_bpermute(bpa1, (int)pk[mi][hi_][1]);
                pt.u[3] = (quad < 2) ? a3 : b3;
                pT[mi][sk] = pt.s8;
            }
        // ---- O^T += V^T P^T ----
        __builtin_amdgcn_s_setprio(1);
#pragma unroll
        for (int sk = 0; sk < 2; ++sk)
#pragma unroll
            for (int hi = 0; hi < 8; ++hi) {
                short8 vf = *(const short8*)&Vs[cur][(hi * 16 + l15) * 64 + (((sk * 4 + quad) ^ (l15 & 7)) << 3)];
                o[0][hi] = __builtin_amdgcn_mfma_f32_16x16x32_bf16(vf, pT[0][sk], o[0][hi], 0, 0, 0);
                o[1][hi] = __builtin_amdgcn_mfma_f32_16x16x32_bf16(vf, pT[1][sk], o[1][hi], 0, 0, 0);
            }
        __builtin_amdgcn_s_setprio(0);

        // ---- context end? flush segment, start next ----
        if (kv == 2 * qt + 1 || !more) {
            CTX_FLUSH();
            if (more && kv == 2 * qt + 1) CTX_INIT(b2, qt2);
        }
        b = b2; qt = qt2; kv = kv2;
        cur ^= 1;
    }
#undef STAGE_KV
#undef CTX_INIT
#undef CTX_FLUSH
}

// ---------------------------------------------------------------------------
// merge: combine 1..5 fp32 segments per row: out = sum w_j O_j / sum w_j l_j,
// w_j = exp2(m_j - max_j m_j). Seg 0 lives in out (in-place), j>=1 in Oseg.
// ---------------------------------------------------------------------------
__global__ __launch_bounds__(256) void merge_kernel(
    float* __restrict__ out, const float* __restrict__ Oseg,
    const float2* __restrict__ ml)
{
    int idx = blockIdx.x * 256 + threadIdx.x;   // < NROWS*32
    int row = idx >> 5;
    int hc  = (idx & 31) << 2;
    int b = row >> 12, t = row & 4095, qt = t >> 7, rr = t & 127;
    int I0  = b * 1056 + qt * (qt + 1);
    int nkv = 2 * (qt + 1);
    int c_lo = chunk_of(I0);
    int c_hi = chunk_of(I0 + nkv - 1);
    int nseg = c_hi - c_lo + 1;                 // 1..5

    const float2* mlp = ml + ((size_t)(b * 32 + qt) * 5) * 128 + rr;
    float2 s0 = mlp[0];
    float M = s0.x;
    for (int j = 1; j < nseg; ++j) M = fmaxf(M, mlp[(size_t)j * 128].x);

    float w0 = __builtin_amdgcn_exp2f(s0.x - M);
    float L  = w0 * s0.y;
    f32x4 a = *(const f32x4*)&out[(size_t)row * HD + hc];
    a = a * w0;
    for (int j = 1; j < nseg; ++j) {
        float2 mj = mlp[(size_t)j * 128];
        float w = __builtin_amdgcn_exp2f(mj.x - M);
        L += w * mj.y;
        const float* sp = Oseg + ((size_t)(b * 80 + base1(qt) + j - 1) * 128 + rr) * HD + hc;
        f32x4 sv = *(const f32x4*)sp;
        a = a + sv * w;
    }
    float inv = 1.0f / L;
    *(f32x4*)&out[(size_t)row * HD + hc] = a * inv;
}

// ---------------------------------------------------------------------------
extern "C" void kernel_launch(void* const* d_in, const int* in_sizes, int n_in,
                              void* d_out, int out_size, void* d_ws, size_t ws_size,
                              hipStream_t stream) {
    const float* x  = (const float*)d_in[0];
    const float* Wq = (const float*)d_in[1];
    const float* bq = (const float*)d_in[2];
    const float* Wk = (const float*)d_in[3];
    const float* bk = (const float*)d_in[4];
    const float* Wv = (const float*)d_in[5];
    const float* bv = (const float*)d_in[6];
    float* out = (float*)d_out;

    // ws: wt 768K | biasc 1.5K | qb 8.39M | kb 8.39M | vtb 8.39M |
    //     Oseg 640 slots x 128 x 128 f32 = 41.9M | ml 1.31M  (~69.2 MB total)
    unsigned short* wt    = (unsigned short*)d_ws;
    float*          biasc = (float*)((char*)d_ws + 786432);
    unsigned short* qb    = (unsigned short*)((char*)d_ws + 787968);
    unsigned short* kb    = qb  + (size_t)NROWS * HD;
    unsigned short* vtb   = kb  + (size_t)NROWS * HD;
    float*          Oseg  = (float*)((char*)d_ws + 787968 + 3ull * NROWS * HD * 2);
    float2*         mlseg = (float2*)((char*)Oseg + 640ull * 128 * HD * 4);

    prep_kernel<<<dim3(384), 256, 0, stream>>>(Wq, bq, Wk, bk, Wv, bv, wt, biasc);
    gemm_qkv<<<dim3(256), 768, 0, stream>>>(x, wt, biasc, qb, kb, vtb);
    attn_kernel<<<dim3(512), 256, 0, stream>>>(qb, kb, vtb, out, Oseg, mlseg);
    merge_kernel<<<dim3(NROWS * 32 / 256), 256, 0, stream>>>(out, Oseg, mlseg);
}

// Round 4
// 308.595 us; speedup vs baseline: 1.0266x; 1.0266x over previous
//
#include <hip/hip_runtime.h>
#include <hip/hip_bf16.h>
#include <stdint.h>

#define BATCH 8
#define SEQ   4096
#define EMB   1024
#define HD    128
#define NROWS 32768

typedef __attribute__((ext_vector_type(8))) short short8;
typedef __attribute__((ext_vector_type(4))) float f32x4;

__device__ inline unsigned short f2bf(float f) {
    union { float f; unsigned int u; } c; c.f = f;
    unsigned int u = c.u;
    unsigned int r = (u + 0x7fffu + ((u >> 16) & 1u)) >> 16;
    return (unsigned short)r;
}
__device__ inline float bf2f(unsigned short u) {
    union { unsigned int i; float f; } c; c.i = ((unsigned int)u) << 16; return c.f;
}
__device__ inline unsigned int pkbf(float a, float b) {
    __hip_bfloat162 h = __float22bfloat162_rn(make_float2(a, b));
    union { __hip_bfloat162 h; unsigned int u; } c; c.h = h; return c.u;
}

#define GLDS16(gp, lp) __builtin_amdgcn_global_load_lds( \
    (const __attribute__((address_space(1))) void*)(gp), \
    (__attribute__((address_space(3))) void*)(lp), 16, 0, 0)

// ---- stream-K work decomposition (32-key items) ---------------------------
// item = (b, qt, kv32); per batch: sum_qt 4(qt+1) = 2112; total 16896.
// 768 blocks x exactly 22 items. 2112/22 = 96 chunks per batch -> XCD x
// (ranks == x mod 8, chunk = (rank&7)*96 + rank/8) owns exactly batch x.
__device__ inline void decomp(int it, int& b, int& qt, int& kv) {
    b = it / 2112;
    int r = it - b * 2112;
    int q = (int)((__builtin_sqrtf(2.0f * (float)r + 1.0f) - 1.0f) * 0.5f);
    while (2 * (q + 1) * (q + 2) <= r) ++q;
    while (2 * q * (q + 1) > r) --q;
    qt = q;
    kv = r - 2 * q * (q + 1);
}
// overflow-slot base per batch; seg-width bands w=ceil((4qt+25)/22)-1; 112/batch
__device__ inline int base1(int qt) {
    if (qt < 5)  return qt;
    if (qt < 11) return 5 + 2 * (qt - 5);
    if (qt < 16) return 17 + 3 * (qt - 11);
    if (qt < 22) return 32 + 4 * (qt - 16);
    if (qt < 27) return 56 + 5 * (qt - 22);
    return 81 + 6 * (qt - 27);
}

// ---------------------------------------------------------------------------
// prep: wt[n][k] = bf16(W[k][h]) for n = sel*128+h. 384 blocks, one row each.
// ---------------------------------------------------------------------------
__global__ __launch_bounds__(256) void prep_kernel(
    const float* __restrict__ Wq, const float* __restrict__ bq,
    const float* __restrict__ Wk, const float* __restrict__ bk,
    const float* __restrict__ Wv, const float* __restrict__ bv,
    unsigned short* __restrict__ wt, float* __restrict__ biasc)
{
    const int n = blockIdx.x;           // 0..383
    const int sel = n >> 7, h = n & 127;
    const float* W = (sel == 0) ? Wq : (sel == 1) ? Wk : Wv;
    const int tid = threadIdx.x;
    const int k0 = tid * 4;
    union { unsigned short us[4]; uint2 v; } pk;
#pragma unroll
    for (int u = 0; u < 4; ++u) pk.us[u] = f2bf(W[(size_t)(k0 + u) * HD + h]);
    *(uint2*)&wt[(size_t)n * EMB + k0] = pk.v;
    if (tid == 0) {
        const float* bp = (sel == 0) ? bq : (sel == 1) ? bk : bv;
        biasc[n] = bp[h];
    }
}

// ---------------------------------------------------------------------------
// gemm_qkv v2: fused QKV. 256 blocks x 128 rows x all 384 cols; 12 waves
// (768 thr), wave tile 64 rows x 64 cols, acc[4][4].
// ---------------------------------------------------------------------------
__global__ __launch_bounds__(768, 3) void gemm_qkv(
    const float* __restrict__ x, const unsigned short* __restrict__ wt,
    const float* __restrict__ biasc,
    unsigned short* __restrict__ q, unsigned short* __restrict__ kOut,
    unsigned short* __restrict__ vt)
{
    const int m0  = blockIdx.x * 128;
    const int tid = threadIdx.x;
    const int wave = tid >> 6, lane = tid & 63;
    const int quad = lane >> 4, l15 = lane & 15;
    const int wm = (wave >= 6) ? 1 : 0;      // 2 M-waves x 6 N-waves
    const int wn = wave - wm * 6;            // 0..5, 64 cols each

    __shared__ __align__(16) unsigned short As[2][128][40];   // +8 pad
    __shared__ __align__(16) unsigned short Bs[2][12288];     // [384][32] swizzled

    f32x4 acc[4][4];
#pragma unroll
    for (int i = 0; i < 4; ++i)
#pragma unroll
        for (int j = 0; j < 4; ++j) acc[i][j] = (f32x4){0.f, 0.f, 0.f, 0.f};

    const int aactive = (tid < 512);
    const int arow = tid >> 3, akc = (tid & 7) * 4;
    float4 aR0, aR1;

#define LOAD_A(kt)                                                          \
    if (aactive) {                                                          \
        aR0 = *(const float4*)(x + (size_t)(m0 + arow) * EMB + (kt) * 32 + akc);        \
        aR1 = *(const float4*)(x + (size_t)(m0 + arow + 64) * EMB + (kt) * 32 + akc);   \
    }
#define WRITE_A(buf)                                                        \
    if (aactive) {                                                          \
        union { unsigned short us[4]; uint2 v; } p0, p1;                    \
        p0.us[0] = f2bf(aR0.x); p0.us[1] = f2bf(aR0.y);                     \
        p0.us[2] = f2bf(aR0.z); p0.us[3] = f2bf(aR0.w);                     \
        *(uint2*)&As[buf][arow][akc] = p0.v;                                \
        p1.us[0] = f2bf(aR1.x); p1.us[1] = f2bf(aR1.y);                     \
        p1.us[2] = f2bf(aR1.z); p1.us[3] = f2bf(aR1.w);                     \
        *(uint2*)&As[buf][arow + 64][akc] = p1.v;                           \
    }
#define STAGE_B(kt, buf)                                                    \
    {                                                                       \
        _Pragma("unroll")                                                   \
        for (int g = 0; g < 2; ++g) {                                       \
            int s0 = (g * 12 + wave) * 64;                                  \
            int s  = s0 + lane;                                             \
            int n  = s >> 2, c = (s & 3) ^ (n & 3);                         \
            GLDS16(wt + (size_t)n * EMB + (kt) * 32 + c * 8,                \
                   &Bs[buf][s0 * 8]);                                       \
        }                                                                   \
    }

    LOAD_A(0); STAGE_B(0, 0); WRITE_A(0);
    int cur = 0;

    for (int kt = 0; kt < 32; ++kt) {
        __syncthreads();
        if (kt < 31) { LOAD_A(kt + 1); STAGE_B(kt + 1, cur ^ 1); }
        short8 af[4], bw[4];
#pragma unroll
        for (int mj = 0; mj < 4; ++mj)
            af[mj] = *(const short8*)&As[cur][wm * 64 + mj * 16 + l15][quad * 8];
#pragma unroll
        for (int ni = 0; ni < 4; ++ni) {
            int n = wn * 64 + ni * 16 + l15;
            bw[ni] = *(const short8*)&Bs[cur][n * 32 + ((quad ^ (n & 3)) << 3)];
        }
#pragma unroll
        for (int ni = 0; ni < 4; ++ni)
#pragma unroll
            for (int mj = 0; mj < 4; ++mj)
                acc[ni][mj] = __builtin_amdgcn_mfma_f32_16x16x32_bf16(
                    bw[ni], af[mj], acc[ni][mj], 0, 0, 0);
        if (kt < 31) WRITE_A(cur ^ 1);
        cur ^= 1;
    }

    const float qscale = 0.08838834764831845f * 1.4426950408889634f;
    const int bb = m0 >> 12;
    const int t0 = m0 & 4095;
    const int mrow0 = m0 + wm * 64;
    const int tl0   = t0 + wm * 64;
#pragma unroll
    for (int ni = 0; ni < 4; ++ni) {
        int colbase = wn * 64 + ni * 16;
        int sel = colbase >> 7;
        int c0 = colbase + quad * 4;
        float4 bv4 = *(const float4*)&biasc[c0];
#pragma unroll
        for (int mj = 0; mj < 4; ++mj) {
            int m = mrow0 + mj * 16 + l15;
            if (sel == 0) {
                union { unsigned short us[4]; uint2 v; } pk;
#pragma unroll
                for (int j = 0; j < 4; ++j)
                    pk.us[j] = f2bf((acc[ni][mj][j] + ((const float*)&bv4)[j]) * qscale);
                *(uint2*)&q[(size_t)m * HD + (c0 & 127)] = pk.v;
            } else if (sel == 1) {
                union { unsigned short us[4]; uint2 v; } pk;
#pragma unroll
                for (int j = 0; j < 4; ++j)
                    pk.us[j] = f2bf(acc[ni][mj][j] + ((const float*)&bv4)[j]);
                *(uint2*)&kOut[(size_t)m * HD + (c0 & 127)] = pk.v;
            } else {
#pragma unroll
                for (int j = 0; j < 4; ++j) {
                    int h = (c0 & 127) + j;
                    vt[((size_t)(bb * 128 + h)) * SEQ + tl0 + mj * 16 + l15] =
                        f2bf(acc[ni][mj][j] + ((const float*)&bv4)[j]);
                }
            }
        }
    }
#undef LOAD_A
#undef WRITE_A
#undef STAGE_B
}

// ---------------------------------------------------------------------------
// attn v4: stream-K flash attention, 32-key items. 768 blocks x 256 thr
// (4 waves), LDS 32KB -> 3 blocks/CU = 3 waves/SIMD (v3's invariant: ~83us
// at 2 waves/SIMD across three schedules = latency-bound chain; this raises
// residency 1.5x and halves the per-item chain). Exactly 22 items/block.
// chunk = (rank&7)*96 + rank/8: each XCD owns one batch (K+V+Q ~3MB, L2-
// resident) to undo v3's FETCH_SIZE 10x regression. Per-wave skip of fully
// masked tiles. Segments flushed fp32; merge combines 1..7.
// ---------------------------------------------------------------------------
__global__ __launch_bounds__(256, 3) void attn_kernel(
    const unsigned short* __restrict__ q, const unsigned short* __restrict__ k,
    const unsigned short* __restrict__ vt, float* __restrict__ out,
    float* __restrict__ Oseg, float2* __restrict__ ml)
{
    const int rank  = blockIdx.x;                       // 0..767
    const int chunk = (rank & 7) * 96 + (rank >> 3);    // XCD-contiguous
    const int start = chunk * 22;
    const int iend  = start + 22;

    const int tid  = threadIdx.x;
    const int wave = tid >> 6, lane = tid & 63;
    const int quad = lane >> 4, l15 = lane & 15;

    __shared__ __align__(16) unsigned short Ks[2][4096];  // [32 key][16 ch8 sw]
    __shared__ __align__(16) unsigned short Vs[2][4096];  // [128 h][4 ch8 sw]

    const int bpa0 = (l15 + 16 * ((2 * quad) & 3)) * 4;   // bpermute byte addrs
    const int bpa1 = (l15 + 16 * ((2 * quad + 1) & 3)) * 4;

#define STAGE_KV(b_, kv_, buf_)                                              \
    {                                                                        \
        const size_t kb0 = (size_t)(b_) * SEQ + (kv_) * 32;                  \
        const size_t vb0 = (size_t)(b_) * HD * SEQ + (kv_) * 32;             \
        _Pragma("unroll")                                                    \
        for (int g = 0; g < 2; ++g) {                                        \
            int s0 = (g * 4 + wave) * 64;                                    \
            int s  = s0 + lane;                                              \
            int key = s >> 4, c = (s & 15) ^ (key & 15);                     \
            GLDS16(k + (kb0 + key) * HD + c * 8, &Ks[buf_][s0 * 8]);         \
        }                                                                    \
        _Pragma("unroll")                                                    \
        for (int g = 0; g < 2; ++g) {                                        \
            int s0 = (g * 4 + wave) * 64;                                    \
            int s  = s0 + lane;                                              \
            int h = s >> 2, c = (s & 3) ^ ((h >> 2) & 3);                    \
            GLDS16(vt + vb0 + (size_t)h * SEQ + c * 8, &Vs[buf_][s0 * 8]);   \
        }                                                                    \
    }

    int b, qt, kv;
    decomp(start, b, qt, kv);

    short8 qf[2][4];
    f32x4  o[2][8];
    float  m_r[2], l_r[2];
    int    qrow0 = 0;

#define CTX_INIT(b_, q_)                                                     \
    {                                                                        \
        qrow0 = (q_) * 128 + wave * 32;                                      \
        const size_t qoff = (size_t)(b_) * SEQ + qrow0;                      \
        _Pragma("unroll")                                                    \
        for (int mi = 0; mi < 2; ++mi)                                       \
            _Pragma("unroll")                                                \
            for (int kh = 0; kh < 4; ++kh)                                   \
                qf[mi][kh] = *(const short8*)(q + (qoff + mi * 16 + l15) * HD + kh * 32 + quad * 8); \
        _Pragma("unroll")                                                    \
        for (int mi = 0; mi < 2; ++mi) {                                     \
            _Pragma("unroll")                                                \
            for (int hi = 0; hi < 8; ++hi) o[mi][hi] = (f32x4){0.f, 0.f, 0.f, 0.f}; \
            m_r[mi] = -1e30f; l_r[mi] = 0.f;                                 \
        }                                                                    \
    }

#define CTX_FLUSH()                                                          \
    {                                                                        \
        const int I0 = b * 2112 + 2 * qt * (qt + 1);                         \
        const int j  = chunk - I0 / 22;                                      \
        const int rr = wave * 32;                                            \
        float* obase;                                                        \
        if (j == 0) obase = out + ((size_t)b * SEQ + qrow0) * HD;            \
        else obase = Oseg + ((size_t)(b * 112 + base1(qt) + j - 1) * 128 + rr) * HD; \
        const size_t mlb = ((size_t)(b * 32 + qt) * 7 + j) * 128 + rr;       \
        _Pragma("unroll")                                                    \
        for (int mi = 0; mi < 2; ++mi) {                                     \
            if (quad == 0) ml[mlb + mi * 16 + l15] = make_float2(m_r[mi], l_r[mi]); \
            _Pragma("unroll")                                                \
            for (int hi = 0; hi < 8; ++hi)                                   \
                *(f32x4*)&obase[(size_t)(mi * 16 + l15) * HD + hi * 16 + quad * 4] = o[mi][hi]; \
        }                                                                    \
    }

    STAGE_KV(b, kv, 0);
    CTX_INIT(b, qt);
    int cur = 0;

    for (int it = start; it < iend; ++it) {
        int b2 = 0, qt2 = 0, kv2 = 0;
        const bool more = (it + 1 < iend);
        if (more) decomp(it + 1, b2, qt2, kv2);

        __syncthreads();                     // buf[cur] staged; prev reads retired
        if (more) STAGE_KV(b2, kv2, cur ^ 1);

        const int key0 = kv * 32;
        if (key0 <= qrow0 + 31) {            // skip fully-masked tiles (wave-local)
            // ---- S^T = K Q^T : D[key][qrow], lane=qrow, regs=keys ----
            f32x4 s[2][2];
#pragma unroll
            for (int mi = 0; mi < 2; ++mi)
#pragma unroll
                for (int ni = 0; ni < 2; ++ni) s[mi][ni] = (f32x4){0.f, 0.f, 0.f, 0.f};
            __builtin_amdgcn_s_setprio(1);
#pragma unroll
            for (int kh = 0; kh < 4; ++kh) {
#pragma unroll
                for (int ni = 0; ni < 2; ++ni) {
                    short8 kf = *(const short8*)&Ks[cur][(ni * 16 + l15) * 128 + (((kh * 4 + quad) ^ l15) << 3)];
                    s[0][ni] = __builtin_amdgcn_mfma_f32_16x16x32_bf16(kf, qf[0][kh], s[0][ni], 0, 0, 0);
                    s[1][ni] = __builtin_amdgcn_mfma_f32_16x16x32_bf16(kf, qf[1][kh], s[1][ni], 0, 0, 0);
                }
            }
            __builtin_amdgcn_s_setprio(0);
            // ---- causal mask (diagonal tiles only) ----
            if (key0 + 31 > qrow0) {
#pragma unroll
                for (int mi = 0; mi < 2; ++mi)
#pragma unroll
                    for (int ni = 0; ni < 2; ++ni)
#pragma unroll
                        for (int j = 0; j < 4; ++j) {
                            int key = key0 + ni * 16 + quad * 4 + j;
                            int t   = qrow0 + mi * 16 + l15;
                            if (key > t) s[mi][ni][j] = -1e30f;
                        }
            }
            // ---- online softmax (scalar per lane) + P pack, defer-max ----
            unsigned int pk[2][2][2];
#pragma unroll
            for (int mi = 0; mi < 2; ++mi) {
                float mx = -1e30f;
#pragma unroll
                for (int ni = 0; ni < 2; ++ni)
#pragma unroll
                    for (int j = 0; j < 4; ++j) mx = fmaxf(mx, s[mi][ni][j]);
                mx = fmaxf(mx, __shfl_xor(mx, 16));
                mx = fmaxf(mx, __shfl_xor(mx, 32));
                if (!__all(mx - m_r[mi] <= 8.0f)) {
                    float mnew = fmaxf(m_r[mi], mx);
                    float alpha = __builtin_amdgcn_exp2f(m_r[mi] - mnew);
                    m_r[mi] = mnew;
                    l_r[mi] *= alpha;
#pragma unroll
                    for (int hi = 0; hi < 8; ++hi) o[mi][hi] *= alpha;
                }
                const float mcur = m_r[mi];
                float rs = 0.f;
#pragma unroll
                for (int ni = 0; ni < 2; ++ni) {
                    float p0 = __builtin_amdgcn_exp2f(s[mi][ni][0] - mcur);
                    float p1 = __builtin_amdgcn_exp2f(s[mi][ni][1] - mcur);
                    float p2 = __builtin_amdgcn_exp2f(s[mi][ni][2] - mcur);
                    float p3 = __builtin_amdgcn_exp2f(s[mi][ni][3] - mcur);
                    rs += (p0 + p1) + (p2 + p3);
                    pk[mi][ni][0] = pkbf(p0, p1);
                    pk[mi][ni][1] = pkbf(p2, p3);
                }
                rs += __shfl_xor(rs, 16);
                rs += __shfl_xor(rs, 32);
                l_r[mi] += rs;
            }
            // ---- P^T B-frags via cross-quad bpermute (32 keys -> 1 frag/mi) ----
            short8 pT[2];
#pragma unroll
            for (int mi = 0; mi < 2; ++mi) {
                union { unsigned int u[4]; short8 s8; } pt;
                unsigned int a0 = (unsigned)__builtin_amdgcn_ds_bpermute(bpa0, (int)pk[mi][0][0]);
                unsigned int b0 = (unsigned)__builtin_amdgcn_ds_bpermute(bpa0, (int)pk[mi][1][0]);
                pt.u[0] = (quad < 2) ? a0 : b0;
                unsigned int a1 = (unsigned)__builtin_amdgcn_ds_bpermute(bpa0, (int)pk[mi][0][1]);
                unsigned int b1 = (unsigned)__builtin_amdgcn_ds_bpermute(bpa0, (int)pk[mi][1][1]);
                pt.u[1] = (quad < 2) ? a1 : b1;
                unsigned int a2 = (unsigned)__builtin_amdgcn_ds_bpermute(bpa1, (int)pk[mi][0][0]);
                unsigned int b2 = (unsigned)__builtin_amdgcn_ds_bpermute(bpa1, (int)pk[mi][1][0]);
                pt.u[2] = (quad < 2) ? a2 : b2;
                unsigned int a3 = (unsigned)__builtin_amdgcn_ds_bpermute(bpa1, (int)pk[mi][0][1]);
                unsigned int b3 = (unsigned)__builtin_amdgcn_ds_bpermute(bpa1, (int)pk[mi][1][1]);
                pt.u[3] = (quad < 2) ? a3 : b3;
                pT[mi] = pt.s8;
            }
            // ---- O^T += V^T P^T ----
            __builtin_amdgcn_s_setprio(1);
#pragma unroll
            for (int hi = 0; hi < 8; ++hi) {
                short8 vf = *(const short8*)&Vs[cur][(hi * 16 + l15) * 32 + ((quad ^ (l15 >> 2)) << 3)];
                o[0][hi] = __builtin_amdgcn_mfma_f32_16x16x32_bf16(vf, pT[0], o[0][hi], 0, 0, 0);
                o[1][hi] = __builtin_amdgcn_mfma_f32_16x16x32_bf16(vf, pT[1], o[1][hi], 0, 0, 0);
            }
            __builtin_amdgcn_s_setprio(0);
        }

        // ---- context end? flush segment, start next ----
        if (kv == 4 * qt + 3 || !more) {
            CTX_FLUSH();
            if (more && kv == 4 * qt + 3) CTX_INIT(b2, qt2);
        }
        b = b2; qt = qt2; kv = kv2;
        cur ^= 1;
    }
#undef STAGE_KV
#undef CTX_INIT
#undef CTX_FLUSH
}

// ---------------------------------------------------------------------------
// merge: combine 1..7 fp32 segments per row: out = sum w_j O_j / sum w_j l_j,
// w_j = exp2(m_j - max_j m_j). Seg 0 lives in out (in-place), j>=1 in Oseg.
// ---------------------------------------------------------------------------
__global__ __launch_bounds__(256) void merge_kernel(
    float* __restrict__ out, const float* __restrict__ Oseg,
    const float2* __restrict__ ml)
{
    int idx = blockIdx.x * 256 + threadIdx.x;   // < NROWS*32
    int row = idx >> 5;
    int hc  = (idx & 31) << 2;
    int b = row >> 12, t = row & 4095, qt = t >> 7, rr = t & 127;
    int I0   = b * 2112 + 2 * qt * (qt + 1);
    int n    = 4 * (qt + 1);
    int nseg = (I0 + n - 1) / 22 - I0 / 22 + 1;   // 1..7

    const float2* mlp = ml + ((size_t)(b * 32 + qt) * 7) * 128 + rr;
    float2 s0 = mlp[0];
    float M = s0.x;
    for (int j = 1; j < nseg; ++j) M = fmaxf(M, mlp[(size_t)j * 128].x);

    float w0 = __builtin_amdgcn_exp2f(s0.x - M);
    float L  = w0 * s0.y;
    f32x4 a = *(const f32x4*)&out[(size_t)row * HD + hc];
    a = a * w0;
    for (int j = 1; j < nseg; ++j) {
        float2 mj = mlp[(size_t)j * 128];
        float w = __builtin_amdgcn_exp2f(mj.x - M);
        L += w * mj.y;
        const float* sp = Oseg + ((size_t)(b * 112 + base1(qt) + j - 1) * 128 + rr) * HD + hc;
        f32x4 sv = *(const f32x4*)sp;
        a = a + sv * w;
    }
    float inv = 1.0f / L;
    *(f32x4*)&out[(size_t)row * HD + hc] = a * inv;
}

// ---------------------------------------------------------------------------
extern "C" void kernel_launch(void* const* d_in, const int* in_sizes, int n_in,
                              void* d_out, int out_size, void* d_ws, size_t ws_size,
                              hipStream_t stream) {
    const float* x  = (const float*)d_in[0];
    const float* Wq = (const float*)d_in[1];
    const float* bq = (const float*)d_in[2];
    const float* Wk = (const float*)d_in[3];
    const float* bk = (const float*)d_in[4];
    const float* Wv = (const float*)d_in[5];
    const float* bv = (const float*)d_in[6];
    float* out = (float*)d_out;

    // ws: wt 768K | biasc 1.5K | qb 8.39M | kb 8.39M | vtb 8.39M |
    //     Oseg 896 slots x 128 x 128 f32 = 58.7M | ml 1.84M  (~86.5 MB total)
    unsigned short* wt    = (unsigned short*)d_ws;
    float*          biasc = (float*)((char*)d_ws + 786432);
    unsigned short* qb    = (unsigned short*)((char*)d_ws + 787968);
    unsigned short* kb    = qb  + (size_t)NROWS * HD;
    unsigned short* vtb   = kb  + (size_t)NROWS * HD;
    float*          Oseg  = (float*)((char*)d_ws + 787968 + 3ull * NROWS * HD * 2);
    float2*         mlseg = (float2*)((char*)Oseg + 896ull * 128 * HD * 4);

    prep_kernel<<<dim3(384), 256, 0, stream>>>(Wq, bq, Wk, bk, Wv, bv, wt, biasc);
    gemm_qkv<<<dim3(256), 768, 0, stream>>>(x, wt, biasc, qb, kb, vtb);
    attn_kernel<<<dim3(768), 256, 0, stream>>>(qb, kb, vtb, out, Oseg, mlseg);
    merge_kernel<<<dim3(NROWS * 32 / 256), 256, 0, stream>>>(out, Oseg, mlseg);
}